// Round 1
// baseline (736.223 us; speedup 1.0000x reference)
//
#include <hip/hip_runtime.h>

// ---------------------------------------------------------------------------
// QGroupLinear: y[m,n] = sum_k x[m,k] * (qw[n,k] * sw[n, k/G]) + bias[n]
// M=4096 (B*S), K=4096, N=11008, G=128.
// R4: GEMM ported to the 256x256 8-phase counted-vmcnt template
//     (T1 XCD swizzle + T2 XOR-swizzled LDS + T3/T4 phase-split with
//     vmcnt(4) checkpoints, never 0 in main loop + T5 setprio around MFMA).
//     512 threads / 8 waves (2Mx4N), BK=64, 128 KiB LDS double-buffer.
//     Ledger: B(T+1) staged ph0/1 -> other buffer; A(T+2) staged ph2/3 ->
//     current buffer (safe: all A ds_reads complete by ph1 lgkmcnt+barrier).
//     Tail tiles (no A prefetch) drain vmcnt(0) once - correctness.
// R4b: prep kernel indexing via shifts (no 64-bit runtime division).
// ---------------------------------------------------------------------------

typedef __attribute__((ext_vector_type(8))) short short8;
typedef __attribute__((ext_vector_type(4))) float floatx4;

__device__ __forceinline__ unsigned short f2bf_rne(float f) {
  union { float f; unsigned int u; } c;
  c.f = f;
  unsigned int u = c.u;
  u += 0x7FFFu + ((u >> 16) & 1u);   // round-to-nearest-even
  return (unsigned short)(u >> 16);
}

// ---- merged preprocess: xb = bf16(x); wb = bf16(qw * sw) ------------------
__global__ void prep_kernel(const float* __restrict__ x,
                            const int* __restrict__ qw,
                            const float* __restrict__ sw,
                            short* __restrict__ xb,
                            short* __restrict__ wb,
                            long nx_chunks, long total_chunks,
                            int K, int kshift, int gshift, int G, int ngroups) {
  long stride = (long)gridDim.x * blockDim.x;
  for (long c = (long)blockIdx.x * blockDim.x + threadIdx.x;
       c < total_chunks; c += stride) {
    if (c < nx_chunks) {
      long i = c * 8;
      const float4* p = (const float4*)(x + i);
      float4 a = p[0], b = p[1];
      short8 o;
      o[0] = (short)f2bf_rne(a.x); o[1] = (short)f2bf_rne(a.y);
      o[2] = (short)f2bf_rne(a.z); o[3] = (short)f2bf_rne(a.w);
      o[4] = (short)f2bf_rne(b.x); o[5] = (short)f2bf_rne(b.y);
      o[6] = (short)f2bf_rne(b.z); o[7] = (short)f2bf_rne(b.w);
      *(short8*)(xb + i) = o;
    } else {
      long e = (c - nx_chunks) * 8;
      int n, k;
      if (kshift >= 0) {
        n = (int)(e >> kshift);
        k = (int)(e & (long)(K - 1));
      } else {
        n = (int)(e / K);
        k = (int)(e - (long)n * K);
      }
      int g = (gshift >= 0) ? (k >> gshift) : (k / G);
      const int* q = qw + (long)n * K + k;
      float s = sw[(long)n * ngroups + g];   // G % 8 == 0 guaranteed by caller
      int4 q0 = *(const int4*)q;
      int4 q1 = *(const int4*)(q + 4);
      short8 o;
      o[0] = (short)f2bf_rne((float)q0.x * s);
      o[1] = (short)f2bf_rne((float)q0.y * s);
      o[2] = (short)f2bf_rne((float)q0.z * s);
      o[3] = (short)f2bf_rne((float)q0.w * s);
      o[4] = (short)f2bf_rne((float)q1.x * s);
      o[5] = (short)f2bf_rne((float)q1.y * s);
      o[6] = (short)f2bf_rne((float)q1.z * s);
      o[7] = (short)f2bf_rne((float)q1.w * s);
      *(short8*)(wb + e) = o;
    }
  }
}

// ---- 8-phase 256x256 bf16 MFMA GEMM: Y = Xb * Wb^T + bias -----------------
#define BM 256
#define BN 256
#define BK 64

// Stage one 128-row x 64-col (bf16) half-tile into LDS via global_load_lds.
// LDS dest is linear (HW: wave-uniform base + lane*16); the XOR swizzle
// (chunk ^= row&7) is applied by pre-swizzling the GLOBAL source column.
__device__ __forceinline__ void stage_half(const short* __restrict__ src,
                                           int rowbase, int k0, int K,
                                           short* dst, int t) {
#pragma unroll
  for (int j = 0; j < 2; ++j) {
    const int c = (j << 9) | t;          // 0..1023 chunk id (16B chunks)
    const int r = c >> 3;                // row 0..127
    const int g = (c & 7) ^ (r & 7);     // global k-chunk for this slot
    __builtin_amdgcn_global_load_lds(
        (const __attribute__((address_space(1))) void*)(
            src + (long)(rowbase + r) * K + k0 + (g << 3)),
        (__attribute__((address_space(3))) void*)(dst + (c << 3)),
        16, 0, 0);
  }
}

__global__ __launch_bounds__(512, 2) void gemm8p_kernel(
    const short* __restrict__ Xb,    // [M][K] bf16 bits
    const short* __restrict__ Wb,    // [N][K] bf16 bits
    const float* __restrict__ bias,  // [N]
    float* __restrict__ Y,           // [M][N]
    int M, int N, int K) {
  // [buf][half][row*64 + swizzled-chunk*8] ; 64 KB + 64 KB = 128 KiB
  __shared__ short As[2][2][128 * 64];
  __shared__ short Bs[2][2][128 * 64];

  const int t = threadIdx.x;       // 0..511
  const int wave = t >> 6;         // 0..7
  const int lane = t & 63;
  const int wm = wave >> 2;        // 0..1  (A half / M 128-stripe)
  const int wn = wave & 3;         // 0..3  (N 64-stripe)
  const int quad = lane >> 4;      // 0..3
  const int l16 = lane & 15;

  // ---- XCD-aware swizzle: xcd owns 2 consecutive M-tiles, sweeps N with
  // M-interleave so each B panel is L2-hot for 2 consecutive blocks.
  const int gm = M / BM, gn = N / BN;
  int bid = (int)blockIdx.x;
  int mt, nt;
  if ((gm & 7) == 0) {
    int stripe = gm >> 3;
    int xcd = bid & 7;
    int q = bid >> 3;
    mt = xcd * stripe + q % stripe;
    nt = q / stripe;
  } else {
    mt = bid % gm;
    nt = bid / gm;
  }
  const long tileM = (long)mt * BM;
  const long tileN = (long)nt * BN;

  const short* __restrict__ Ag = Xb + tileM * K;
  const short* __restrict__ Bg = Wb + tileN * K;

  floatx4 acc[8][4];
#pragma unroll
  for (int i = 0; i < 8; ++i)
#pragma unroll
    for (int j = 0; j < 4; ++j) acc[i][j] = {0.f, 0.f, 0.f, 0.f};

  const int NT = K / BK;

  // ---- prologue: stage A(t0), B(t0), A(t1); keep A(t1) in flight ----------
  stage_half(Ag,   0,  0, K, &As[0][0][0], t);
  stage_half(Ag, 128,  0, K, &As[0][1][0], t);
  stage_half(Bg,   0,  0, K, &Bs[0][0][0], t);
  stage_half(Bg, 128,  0, K, &Bs[0][1][0], t);
  stage_half(Ag,   0, BK, K, &As[1][0][0], t);
  stage_half(Ag, 128, BK, K, &As[1][1][0], t);
  asm volatile("s_waitcnt vmcnt(4)" ::: "memory");
  __builtin_amdgcn_sched_barrier(0);
  __builtin_amdgcn_s_barrier();

  // fragment read offsets: global chunk (ks*4 + quad) at row r -> physical
  // chunk ^= (r&7); r&7 == l16&7 (frag row = i*16 + l16). ks1 = ks0 ^ 32.
  const int c0 = (quad ^ (l16 & 7)) << 3;   // shorts
  const int c1 = c0 ^ 32;
  const int nb = (wn & 1) * 64;             // n-row base inside B half

  for (int T = 0; T < NT; ++T) {
    const int buf = T & 1;
    const short* Ab = &As[buf][wm][0];
    const short* Bb = &Bs[buf][wn >> 1][0];
    short8 a0[8], a1[8], b0[4], b1[4];

    // ============ phase 0: read ks0 frags | stage B(T+1).h0 | MFMA m0-3,ks0
#pragma unroll
    for (int i = 0; i < 8; ++i)
      a0[i] = *(const short8*)(Ab + (i * 16 + l16) * 64 + c0);
#pragma unroll
    for (int j = 0; j < 4; ++j)
      b0[j] = *(const short8*)(Bb + (nb + j * 16 + l16) * 64 + c0);
    if (T + 1 < NT)
      stage_half(Bg, 0, (T + 1) * BK, K, &Bs[buf ^ 1][0][0], t);
    __builtin_amdgcn_sched_barrier(0);
    __builtin_amdgcn_s_barrier();
    asm volatile("s_waitcnt lgkmcnt(0)" ::: "memory");
    __builtin_amdgcn_sched_barrier(0);
    __builtin_amdgcn_s_setprio(1);
#pragma unroll
    for (int i = 0; i < 4; ++i)
#pragma unroll
      for (int j = 0; j < 4; ++j)
        acc[i][j] = __builtin_amdgcn_mfma_f32_16x16x32_bf16(a0[i], b0[j],
                                                            acc[i][j], 0, 0, 0);
    __builtin_amdgcn_s_setprio(0);
    __builtin_amdgcn_sched_barrier(0);
    __builtin_amdgcn_s_barrier();

    // ============ phase 1: read ks1 frags | stage B(T+1).h1 | MFMA m4-7,ks0
#pragma unroll
    for (int i = 0; i < 8; ++i)
      a1[i] = *(const short8*)(Ab + (i * 16 + l16) * 64 + c1);
#pragma unroll
    for (int j = 0; j < 4; ++j)
      b1[j] = *(const short8*)(Bb + (nb + j * 16 + l16) * 64 + c1);
    if (T + 1 < NT)
      stage_half(Bg, 128, (T + 1) * BK, K, &Bs[buf ^ 1][1][0], t);
    __builtin_amdgcn_sched_barrier(0);
    __builtin_amdgcn_s_barrier();
    asm volatile("s_waitcnt lgkmcnt(0)" ::: "memory");
    __builtin_amdgcn_sched_barrier(0);
    __builtin_amdgcn_s_setprio(1);
#pragma unroll
    for (int i = 0; i < 4; ++i)
#pragma unroll
      for (int j = 0; j < 4; ++j)
        acc[4 + i][j] = __builtin_amdgcn_mfma_f32_16x16x32_bf16(
            a0[4 + i], b0[j], acc[4 + i][j], 0, 0, 0);
    __builtin_amdgcn_s_setprio(0);
    __builtin_amdgcn_sched_barrier(0);
    __builtin_amdgcn_s_barrier();
    // all A/B ds_reads of this tile are now complete (lgkmcnt(0) + barrier)

    // ============ phase 2: stage A(T+2).h0 (same buf - safe) | MFMA m0-3,ks1
    if (T + 2 < NT)
      stage_half(Ag, 0, (T + 2) * BK, K, &As[buf][0][0], t);
    __builtin_amdgcn_sched_barrier(0);
    __builtin_amdgcn_s_barrier();
    asm volatile("s_waitcnt lgkmcnt(0)" ::: "memory");
    __builtin_amdgcn_sched_barrier(0);
    __builtin_amdgcn_s_setprio(1);
#pragma unroll
    for (int i = 0; i < 4; ++i)
#pragma unroll
      for (int j = 0; j < 4; ++j)
        acc[i][j] = __builtin_amdgcn_mfma_f32_16x16x32_bf16(a1[i], b1[j],
                                                            acc[i][j], 0, 0, 0);
    __builtin_amdgcn_s_setprio(0);
    __builtin_amdgcn_sched_barrier(0);
    __builtin_amdgcn_s_barrier();

    // ============ phase 3: stage A(T+2).h1 | MFMA m4-7,ks1 | vmcnt ckpt
    if (T + 2 < NT)
      stage_half(Ag, 128, (T + 2) * BK, K, &As[buf][1][0], t);
    __builtin_amdgcn_sched_barrier(0);
    __builtin_amdgcn_s_barrier();
    asm volatile("s_waitcnt lgkmcnt(0)" ::: "memory");
    __builtin_amdgcn_sched_barrier(0);
    __builtin_amdgcn_s_setprio(1);
#pragma unroll
    for (int i = 0; i < 4; ++i)
#pragma unroll
      for (int j = 0; j < 4; ++j)
        acc[4 + i][j] = __builtin_amdgcn_mfma_f32_16x16x32_bf16(
            a1[4 + i], b1[j], acc[4 + i][j], 0, 0, 0);
    __builtin_amdgcn_s_setprio(0);
    // once-per-K-tile checkpoint: keep A(T+2) (4 loads) in flight; at the
    // tail (no A prefetch issued) drain so B(T+1) is guaranteed resident.
    if (T + 2 < NT)
      asm volatile("s_waitcnt vmcnt(4)" ::: "memory");
    else
      asm volatile("s_waitcnt vmcnt(0)" ::: "memory");
    __builtin_amdgcn_sched_barrier(0);
    __builtin_amdgcn_s_barrier();
  }

  // ---- epilogue: C/D layout col = l16 (n), row = quad*4 + reg (m) ---------
  const long mbase = tileM + wm * 128;
  const long nbase = tileN + wn * 64;
#pragma unroll
  for (int j = 0; j < 4; ++j) {
    const long n = nbase + j * 16 + l16;
    const float bv = bias[n];
#pragma unroll
    for (int i = 0; i < 8; ++i) {
      const long m0 = mbase + i * 16 + quad * 4;
#pragma unroll
      for (int r = 0; r < 4; ++r)
        Y[(m0 + r) * (long)N + n] = acc[i][j][r] + bv;
    }
  }
}

// ---- fallback (only if ws too small / odd shapes): correct but slow -------
__global__ void naive_kernel(const float* __restrict__ x,
                             const int* __restrict__ qw,
                             const float* __restrict__ sw,
                             const float* __restrict__ bias,
                             float* __restrict__ y,
                             int M, int N, int K, int G) {
  long idx = (long)blockIdx.x * blockDim.x + threadIdx.x;
  if (idx >= (long)M * N) return;
  int m = (int)(idx / N), n = (int)(idx % N);
  int ng = K / G;
  float acc = 0.f;
  for (int g = 0; g < ng; g++) {
    float s = sw[(long)n * ng + g];
    float part = 0.f;
    for (int k = g * G; k < (g + 1) * G; k++)
      part += x[(long)m * K + k] * (float)qw[(long)n * K + k];
    acc += part * s;
  }
  y[idx] = acc + bias[n];
}

extern "C" void kernel_launch(void* const* d_in, const int* in_sizes, int n_in,
                              void* d_out, int out_size, void* d_ws, size_t ws_size,
                              hipStream_t stream) {
  const float* x = (const float*)d_in[0];
  const int* qw = (const int*)d_in[1];
  const float* sw = (const float*)d_in[2];
  const float* bias = (const float*)d_in[3];
  float* y = (float*)d_out;

  const int N = in_sizes[3];
  const int K = in_sizes[1] / N;
  const int M = in_sizes[0] / K;
  const int ngroups = in_sizes[2] / N;
  const int G = K / ngroups;

  const long MK = (long)M * K;
  const long NK = (long)N * K;
  const size_t need = (size_t)(MK + NK) * sizeof(short);

  if (ws_size < need || (M % BM) || (N % BN) || (K % BK) || (K < 2 * BK) ||
      (G % 8)) {
    long total = (long)M * N;
    naive_kernel<<<(unsigned)((total + 255) / 256), 256, 0, stream>>>(
        x, qw, sw, bias, y, M, N, K, G);
    return;
  }

  short* xb = (short*)d_ws;
  short* wb = xb + MK;

  long nx_chunks = MK / 8;
  long total_chunks = nx_chunks + NK / 8;
  int kshift = ((K & (K - 1)) == 0) ? __builtin_ctz((unsigned)K) : -1;
  int gshift = ((G & (G - 1)) == 0) ? __builtin_ctz((unsigned)G) : -1;
  // 2048 blocks (8/CU), grid-stride
  prep_kernel<<<2048, 256, 0, stream>>>(x, qw, sw, xb, wb,
                                        nx_chunks, total_chunks,
                                        K, kshift, gshift, G, ngroups);

  dim3 grid((unsigned)((M / BM) * (N / BN)));
  gemm8p_kernel<<<grid, 512, 0, stream>>>(xb, wb, bias, y, M, N, K);
}